// Round 1
// baseline (622.006 us; speedup 1.0000x reference)
//
#include <hip/hip_runtime.h>
#include <stdint.h>

// ---------------------------------------------------------------------------
// MambaLikeBlock on MI355X (gfx950)
// R7: GEMM rebuilt as 256^2-tile / 512-thread / BK=32 with a 4-slot LDS ring
//     (128 KB), global_load_lds direct staging (pre-swizzled global source,
//     linear LDS dst), 3-tile-deep prefetch with counted s_waitcnt vmcnt()
//     + raw s_barrier (no full drain in steady state), setprio around the
//     MFMA cluster. Previous 128^2 reg-staged loop was latency-bound:
//     MfmaUtil 13%, HBM 11%, ~2000 cyc/iter vs 320 cyc of MFMA work.
// ---------------------------------------------------------------------------

#define L_SEQ 32768
#define CDIM 512
#define LN_EPS 1e-5f
#define CHUNK 64
#define NCHUNK (L_SEQ / CHUNK) // 512

typedef __attribute__((ext_vector_type(8))) short short8;
typedef __attribute__((ext_vector_type(4))) float floatx4;

__device__ inline unsigned short f2bf(float f) {
  union { float f; unsigned int u; } v; v.f = f;
  unsigned int r = v.u + 0x7fffu + ((v.u >> 16) & 1u);
  return (unsigned short)(r >> 16);
}
__device__ inline float bf2f(unsigned short h) {
  union { float f; unsigned int u; } v; v.u = ((unsigned int)h) << 16;
  return v.f;
}
__device__ inline float sigmoidf_(float x) { return 1.0f / (1.0f + __expf(-x)); }

// global -> LDS direct copy, 16B per lane. LDS dst is wave-uniform base +
// lane*16 (hardware); global src is per-lane (carries the swizzle).
__device__ __forceinline__ void gll16(const void* g, void* l) {
  __builtin_amdgcn_global_load_lds(
      (__attribute__((address_space(1))) void*)g,
      (__attribute__((address_space(3))) void*)l, 16, 0, 0);
}

// ---------------- LayerNorm: one wave per row (C=512 = 64 lanes x 8) -------
__global__ __launch_bounds__(256) void ln_kernel(const float* __restrict__ x,
    const float* __restrict__ w, const float* __restrict__ b,
    unsigned short* __restrict__ out) {
  int row = blockIdx.x * 4 + (threadIdx.x >> 6);
  int lane = threadIdx.x & 63;
  const float4* xr = (const float4*)(x + (size_t)row * CDIM);
  float4 v0 = xr[lane * 2];
  float4 v1 = xr[lane * 2 + 1];
  float s = v0.x + v0.y + v0.z + v0.w + v1.x + v1.y + v1.z + v1.w;
  float s2 = v0.x * v0.x + v0.y * v0.y + v0.z * v0.z + v0.w * v0.w +
             v1.x * v1.x + v1.y * v1.y + v1.z * v1.z + v1.w * v1.w;
  for (int m = 32; m > 0; m >>= 1) {
    s += __shfl_xor(s, m, 64);
    s2 += __shfl_xor(s2, m, 64);
  }
  float mean = s * (1.0f / CDIM);
  float var = s2 * (1.0f / CDIM) - mean * mean;
  float rs = rsqrtf(var + LN_EPS);
  const float4* wr = (const float4*)w;
  const float4* br = (const float4*)b;
  float4 w0 = wr[lane * 2], w1 = wr[lane * 2 + 1];
  float4 b0 = br[lane * 2], b1 = br[lane * 2 + 1];
  unsigned int p0 = (unsigned int)f2bf((v0.x - mean) * rs * w0.x + b0.x) |
                    ((unsigned int)f2bf((v0.y - mean) * rs * w0.y + b0.y) << 16);
  unsigned int p1 = (unsigned int)f2bf((v0.z - mean) * rs * w0.z + b0.z) |
                    ((unsigned int)f2bf((v0.w - mean) * rs * w0.w + b0.w) << 16);
  unsigned int p2 = (unsigned int)f2bf((v1.x - mean) * rs * w1.x + b1.x) |
                    ((unsigned int)f2bf((v1.y - mean) * rs * w1.y + b1.y) << 16);
  unsigned int p3 = (unsigned int)f2bf((v1.z - mean) * rs * w1.z + b1.z) |
                    ((unsigned int)f2bf((v1.w - mean) * rs * w1.w + b1.w) << 16);
  uint4 pk; pk.x = p0; pk.y = p1; pk.z = p2; pk.w = p3;
  *((uint4*)(out + (size_t)row * CDIM + lane * 8)) = pk;
}

// ---------------- Combined prep: 5 weight transposes + decay (1 launch) ----
__global__ __launch_bounds__(256) void prep_all(
    const float* __restrict__ W_in, const float* __restrict__ W_gate,
    const float* __restrict__ W_out, const float* __restrict__ W_ff1,
    const float* __restrict__ W_ff2, const float* __restrict__ logit,
    unsigned short* __restrict__ Wt_ig, unsigned short* __restrict__ Wt_out,
    unsigned short* __restrict__ Wt_ff1, unsigned short* __restrict__ Wt_ff2,
    float* __restrict__ decay, float* __restrict__ decayT) {
  int b = blockIdx.x;
  if (b >= 1792) { // decay prep
    for (int c = threadIdx.x; c < CDIM; c += 256) {
      float d = sigmoidf_(logit[c]);
      decay[c] = d;
      float p = d;
      for (int i = 0; i < 6; i++) p *= p; // d^64
      decayT[c] = p;
    }
    return;
  }
  const float* W; unsigned short* Wt; int Kd, Nd, t;
  if (b < 256)       { W = W_in;   Wt = Wt_ig;             Kd = 512;  Nd = 512;  t = b; }
  else if (b < 512)  { W = W_gate; Wt = Wt_ig + 512 * 512; Kd = 512;  Nd = 512;  t = b - 256; }
  else if (b < 768)  { W = W_out;  Wt = Wt_out;            Kd = 512;  Nd = 512;  t = b - 512; }
  else if (b < 1280) { W = W_ff1;  Wt = Wt_ff1;            Kd = 512;  Nd = 1024; t = b - 768; }
  else               { W = W_ff2;  Wt = Wt_ff2;            Kd = 1024; Nd = 512;  t = b - 1280; }
  int ntx = Nd >> 5;
  int n0 = (t % ntx) * 32, k0 = (t / ntx) * 32;
  __shared__ float tile[32][33];
  int tx = threadIdx.x & 31, ty = threadIdx.x >> 5; // 32x8
  for (int r = 0; r < 32; r += 8)
    tile[ty + r][tx] = W[(size_t)(k0 + ty + r) * Nd + n0 + tx];
  __syncthreads();
  for (int r = 0; r < 32; r += 8)
    Wt[(size_t)(n0 + ty + r) * Kd + k0 + tx] = f2bf(tile[tx][ty + r]);
}

// ---------------- bf16 MFMA GEMM: C = A(MxK) * Bt(NxK)^T + epilogue --------
// 256x256 tile, 512 threads = 8 waves (2M x 4N), per-wave 128x64 output
// (8x4 16x16 frags). BK=32. LDS: 4-slot ring for A and B (4 x 16 KB each,
// 128 KB total). Staging is global_load_lds (linear LDS dst, pre-swizzled
// global src); steady-state prefetch depth = 3 K-tiles, guarded by counted
// vmcnt (8 = 2 tiles x 4 loads outstanding allowed) + raw s_barrier.
// EPI 0: n<512 -> outU(bf16) = v+biasA[n]; n>=512 -> outG(bf16)=sigmoid(v+biasB)
// EPI 1: outF = res + v + biasA[n]           (float out, direct stores)
// EPI 2: outG = bf16(silu(v + biasA[n]))     (bf16 out, staged)
template <int EPI>
__global__ __launch_bounds__(512, 2) void gemm256(
    const unsigned short* __restrict__ A, const unsigned short* __restrict__ Bt,
    const float* __restrict__ biasA, const float* __restrict__ biasB,
    const float* __restrict__ res, float* __restrict__ outF,
    unsigned short* __restrict__ outU, unsigned short* __restrict__ outG,
    int M, int N, int K) {
  __shared__ unsigned short smem[65536];       // 128 KB
  unsigned short* As = smem;                   // 4 slots x 8192 elems
  unsigned short* Bs = smem + 32768;           // 4 slots x 8192 elems

  // XCD-aware remap (grid sizes 256/512 are both %8==0 -> bijective)
  int nbx = gridDim.x, nby = gridDim.y;
  int bid = blockIdx.x + blockIdx.y * nbx;
  int per = (nbx * nby) >> 3;
  int w = (bid & 7) * per + (bid >> 3);
  int ni = w % nby, mi = w / nby;
  int bm = mi << 8, bn = ni << 8;

  int tid = threadIdx.x, wave = tid >> 6, lane = tid & 63;
  int wm = (wave >> 2) * 128, wn = (wave & 3) * 64;
  int quad = lane >> 4, r16 = lane & 15;

  // ---- staging addressing ----
  // LDS slot layout (linear): elem = row*32 + chunk*8 + e, rows 0..255.
  // Stored data at [row][chunk] is global k-chunk (chunk ^ ((row>>1)&3)),
  // carried by pre-swizzling the global source column. Read side applies
  // the same XOR -> 2-way-max bank aliasing (free).
  int sr = tid >> 2;             // 0..127 (row within half-tile)
  int sc = tid & 3;              // dst chunk
  int swz = (sr >> 1) & 3;       // same for row sr and sr+128
  const unsigned short* aSrc0 = A + (size_t)(bm + sr) * K + ((sc ^ swz) * 8);
  const unsigned short* aSrc1 = aSrc0 + (size_t)128 * K;
  const unsigned short* bSrc0 = Bt + (size_t)(bn + sr) * K + ((sc ^ swz) * 8);
  const unsigned short* bSrc1 = bSrc0 + (size_t)128 * K;
  int ldsW = wave * 512;         // wave-uniform LDS base (elems); +lane*8 by HW

#define STAGE(slot, ktile) do {                                   \
    int _o = (ktile) * 32;                                        \
    unsigned short* _a = As + (slot) * 8192 + ldsW;               \
    unsigned short* _b = Bs + (slot) * 8192 + ldsW;               \
    gll16(aSrc0 + _o, _a);                                        \
    gll16(aSrc1 + _o, _a + 4096);                                 \
    gll16(bSrc0 + _o, _b);                                        \
    gll16(bSrc1 + _o, _b + 4096);                                 \
  } while (0)

  floatx4 acc[8][4];
#pragma unroll
  for (int i = 0; i < 8; i++)
#pragma unroll
    for (int j = 0; j < 4; j++) acc[i][j] = (floatx4){0.f, 0.f, 0.f, 0.f};

  // fragment read addressing (dewizzle): chunk = quad ^ ((r16>>1)&3)
  int cOff = ((quad ^ ((r16 >> 1) & 3)) & 3) * 8;
  int aBase = (wm + r16) * 32 + cOff;   // + i*512 per m-frag
  int bBase = (wn + r16) * 32 + cOff;   // + j*512 per n-frag

  int NK = K >> 5;  // 16 or 32; needs NK >= 4

  // prologue: stage tiles 0,1,2; wait tile0 (allow 2 tiles = 8 loads out)
  STAGE(0, 0); STAGE(1, 1); STAGE(2, 2);
  asm volatile("s_waitcnt vmcnt(8)" ::: "memory");
  __builtin_amdgcn_s_barrier();
  asm volatile("" ::: "memory");

  for (int j = 0; j < NK; ++j) {
    int slot = j & 3;
    if (j + 3 < NK) STAGE((j + 3) & 3, j + 3);   // ring: overwrites slot (j-1)&3
    const unsigned short* as = As + slot * 8192;
    const unsigned short* bs = Bs + slot * 8192;
    short8 af[8], bfr[4];
#pragma unroll
    for (int i = 0; i < 8; i++) af[i] = *(const short8*)(as + aBase + i * 512);
#pragma unroll
    for (int jj = 0; jj < 4; jj++) bfr[jj] = *(const short8*)(bs + bBase + jj * 512);
    if (j + 1 < NK) {
      // drain this wave's LDS reads (slot j gets overwritten next iter),
      // then guarantee tile j+1's staging landed, then barrier. Counted
      // vmcnt: outstanding allowed = newest tiles only (in-order completion).
      asm volatile("s_waitcnt lgkmcnt(0)" ::: "memory");
      if (j + 3 < NK)      asm volatile("s_waitcnt vmcnt(8)" ::: "memory");
      else if (j + 2 < NK) asm volatile("s_waitcnt vmcnt(4)" ::: "memory");
      else                 asm volatile("s_waitcnt vmcnt(0)" ::: "memory");
      __builtin_amdgcn_s_barrier();
      asm volatile("" ::: "memory");
    }
    __builtin_amdgcn_s_setprio(1);
#pragma unroll
    for (int i = 0; i < 8; i++)
#pragma unroll
      for (int jj = 0; jj < 4; jj++)
        acc[i][jj] = __builtin_amdgcn_mfma_f32_16x16x32_bf16(af[i], bfr[jj], acc[i][jj], 0, 0, 0);
    __builtin_amdgcn_s_setprio(0);
  }
#undef STAGE

  if (EPI == 1) {
    // fp32 output: 16 lanes x 4B = 64B segments, direct stores
#pragma unroll
    for (int i = 0; i < 8; i++) {
      int mb = bm + wm + i * 16 + quad * 4;
#pragma unroll
      for (int jj = 0; jj < 4; jj++) {
        int n = bn + wn + jj * 16 + r16;
        float bA = biasA[n];
#pragma unroll
        for (int r = 0; r < 4; r++) {
          size_t idx = (size_t)(mb + r) * N + n;
          outF[idx] = res[idx] + acc[i][jj][r] + bA;
        }
      }
    }
  } else {
    // bf16 output: stage half the tile (rows {0..63,128..191} then
    // {64..127,192..255}) in LDS, then coalesced 16B/lane stores.
    unsigned short* sm16 = smem;   // 128 rows x 260 elems = 66.6 KB
    for (int p = 0; p < 2; ++p) {
      __syncthreads();   // p0: K-loop LDS reads done; p1: prior stores done
#pragma unroll
      for (int jj = 0; jj < 4; jj++) {
        int colL = wn + jj * 16 + r16;
        int n = bn + colL;
#pragma unroll
        for (int i = 0; i < 4; i++) {
          int ii = p * 4 + i;
          int lr = (wm >> 1) + i * 16 + quad * 4;
#pragma unroll
          for (int r = 0; r < 4; r++) {
            float v = acc[ii][jj][r];
            float t;
            if (EPI == 0) {
              t = (n < 512) ? (v + biasA[n]) : sigmoidf_(v + biasB[n - 512]);
            } else { // EPI == 2
              float z = v + biasA[n];
              t = z * sigmoidf_(z);
            }
            sm16[(lr + r) * 260 + colL] = f2bf(t);
          }
        }
      }
      __syncthreads();
      int row = tid >> 2, c0 = (tid & 3) * 64;
      int gr = bm + (row & 63) + ((row >> 6) * 128) + p * 64;
      const unsigned short* srcp = sm16 + row * 260 + c0;
      unsigned short* gptr;
      if (EPI == 0) {
        gptr = (bn < 512) ? (outU + (size_t)gr * 512 + bn + c0)
                          : (outG + (size_t)gr * 512 + (bn - 512) + c0);
      } else {
        gptr = outG + (size_t)gr * N + bn + c0;
      }
#pragma unroll
      for (int s = 0; s < 8; s++)
        *(short8*)(gptr + s * 8) = *(const short8*)(srcp + s * 8);
    }
  }
}

// ---------------- Scan phase 1: per-chunk fwd/bwd aggregates ---------------
__global__ __launch_bounds__(512) void scan_phase1(const unsigned short* __restrict__ u,
    const float* __restrict__ decay, float* __restrict__ fa, float* __restrict__ ba) {
  int c = threadIdx.x, k = blockIdx.x;
  float d = decay[c];
  const unsigned short* up = u + (size_t)k * CHUNK * CDIM + c;
  float f = 0.f, bs = 0.f, p = 1.f;
#pragma unroll 8
  for (int t = 0; t < CHUNK; t++) {
    float v = bf2f(up[(size_t)t * CDIM]);
    f = d * f + v;
    bs += p * v;
    p *= d;
  }
  fa[(size_t)k * CDIM + c] = f;
  ba[(size_t)k * CDIM + c] = bs;
}

// ---------------- Scan phase 2: cross-chunk carries (fwd/bwd interleaved) --
__global__ __launch_bounds__(256) void scan_phase2(const float* __restrict__ fa,
    const float* __restrict__ ba, const float* __restrict__ decayT,
    float* __restrict__ fc, float* __restrict__ bc) {
  int c = blockIdx.x * 256 + threadIdx.x;
  float dT = decayT[c];
  float runf = 0.f, runb = 0.f;
#pragma unroll 4
  for (int k = 0; k < NCHUNK; k++) {
    int kb = NCHUNK - 1 - k;
    fc[(size_t)k * CDIM + c] = runf;
    runf = dT * runf + fa[(size_t)k * CDIM + c];
    bc[(size_t)kb * CDIM + c] = runb;
    runb = dT * runb + ba[(size_t)kb * CDIM + c];
  }
}

// ---------------- Scan phase 3: apply carries, combine, gate ---------------
__global__ __launch_bounds__(512) void scan_phase3(const unsigned short* __restrict__ u,
    const unsigned short* __restrict__ gate, const float* __restrict__ decay,
    const float* __restrict__ fc, const float* __restrict__ bc,
    unsigned short* __restrict__ state) {
  int c = threadIdx.x, k = blockIdx.x;
  float d = decay[c];
  size_t base = (size_t)k * CHUNK * CDIM + c;
  float fwd[CHUNK];
  float run = fc[(size_t)k * CDIM + c];
#pragma unroll
  for (int t = 0; t < CHUNK; t++) {
    run = d * run + bf2f(u[base + (size_t)t * CDIM]);
    fwd[t] = run;
  }
  float runb = bc[(size_t)k * CDIM + c];
#pragma unroll
  for (int t = CHUNK - 1; t >= 0; t--) {
    runb = d * runb + bf2f(u[base + (size_t)t * CDIM]);
    float g = bf2f(gate[base + (size_t)t * CDIM]);
    state[base + (size_t)t * CDIM] = f2bf(0.5f * (fwd[t] + runb) * g);
  }
}

// ---------------------------------------------------------------------------
extern "C" void kernel_launch(void* const* d_in, const int* in_sizes, int n_in,
                              void* d_out, int out_size, void* d_ws, size_t ws_size,
                              hipStream_t stream) {
  const float* x = (const float*)d_in[0];
  const float* ln1_w = (const float*)d_in[1];
  const float* ln1_b = (const float*)d_in[2];
  const float* W_in = (const float*)d_in[3];
  const float* b_in = (const float*)d_in[4];
  const float* W_gate = (const float*)d_in[5];
  const float* b_gate = (const float*)d_in[6];
  const float* W_out = (const float*)d_in[7];
  const float* b_out = (const float*)d_in[8];
  const float* decay_logit = (const float*)d_in[9];
  const float* ln2_w = (const float*)d_in[10];
  const float* ln2_b = (const float*)d_in[11];
  const float* W_ff1 = (const float*)d_in[12];
  const float* b_ff1 = (const float*)d_in[13];
  const float* W_ff2 = (const float*)d_in[14];
  const float* b_ff2 = (const float*)d_in[15];

  char* ws = (char*)d_ws;
  size_t off = 0;
  auto alloc = [&](size_t bytes) -> void* {
    void* p = ws + off;
    off += (bytes + 255) & ~(size_t)255;
    return p;
  };
  // --- small persistent buffers (~8.5 MB) ---
  unsigned short* Wt_ig  = (unsigned short*)alloc((size_t)1024 * 512 * 2);
  unsigned short* Wt_out = (unsigned short*)alloc((size_t)512 * 512 * 2);
  unsigned short* Wt_ff1 = (unsigned short*)alloc((size_t)1024 * 512 * 2);
  unsigned short* Wt_ff2 = (unsigned short*)alloc((size_t)512 * 1024 * 2);
  float* fa = (float*)alloc((size_t)NCHUNK * CDIM * 4);
  float* ba = (float*)alloc((size_t)NCHUNK * CDIM * 4);
  float* fc = (float*)alloc((size_t)NCHUNK * CDIM * 4);
  float* bc = (float*)alloc((size_t)NCHUNK * CDIM * 4);
  float* decay  = (float*)alloc(CDIM * 4);
  float* decayT = (float*)alloc(CDIM * 4);
  // --- large aliased regions (liveness-disjoint) ---
  const size_t LC2 = (size_t)L_SEQ * CDIM * 2; // 33.55 MB
  unsigned short* R1 = (unsigned short*)alloc(LC2);      // hidden -> state -> hbuf
  unsigned short* R2 = (unsigned short*)alloc(LC2);      // u(bf16) -> ffb[0:]
  unsigned short* R3 = (unsigned short*)alloc(LC2);      // gate    -> ffb[L*C:]
  unsigned short* hidden = R1;
  unsigned short* state  = R1;
  unsigned short* hbuf   = R1;
  unsigned short* u_buf  = R2;
  unsigned short* gate   = R3;
  unsigned short* ffb    = R2; // 67 MB spanning R2+R3 (contiguous)
  float* x2 = (float*)d_out;   // d_out doubles as x2 buffer

  // single prep launch: all transposes + decay
  prep_all<<<1793, 256, 0, stream>>>(W_in, W_gate, W_out, W_ff1, W_ff2,
      decay_logit, Wt_ig, Wt_out, Wt_ff1, Wt_ff2, decay, decayT);

  // LN1
  ln_kernel<<<L_SEQ / 4, 256, 0, stream>>>(x, ln1_w, ln1_b, hidden);

  // u | gate fused GEMM (N=1024); grid = (M/256, N/256)
  gemm256<0><<<dim3(L_SEQ / 256, 1024 / 256), 512, 0, stream>>>(
      hidden, Wt_ig, b_in, b_gate, nullptr, nullptr, u_buf, gate, L_SEQ, 1024, 512);

  // bidirectional scan
  scan_phase1<<<NCHUNK, 512, 0, stream>>>(u_buf, decay, fa, ba);
  scan_phase2<<<2, 256, 0, stream>>>(fa, ba, decayT, fc, bc);
  scan_phase3<<<NCHUNK, 512, 0, stream>>>(u_buf, gate, decay, fc, bc, state);

  // x2 = x + state @ W_out + b_out   (written to d_out)
  gemm256<1><<<dim3(L_SEQ / 256, 512 / 256), 512, 0, stream>>>(
      state, Wt_out, b_out, nullptr, x, x2, nullptr, nullptr, L_SEQ, 512, 512);

  // LN2
  ln_kernel<<<L_SEQ / 4, 256, 0, stream>>>(x2, ln2_w, ln2_b, hbuf);

  // ff = silu(h @ W_ff1 + b_ff1)
  gemm256<2><<<dim3(L_SEQ / 256, 1024 / 256), 512, 0, stream>>>(
      hbuf, Wt_ff1, b_ff1, nullptr, nullptr, nullptr, nullptr, ffb, L_SEQ, 1024, 512);

  // out = x2 + ff @ W_ff2 + b_ff2   (in-place read/write on d_out is per-element safe)
  gemm256<1><<<dim3(L_SEQ / 256, 512 / 256), 512, 0, stream>>>(
      ffb, Wt_ff2, b_ff2, nullptr, x2, x2, nullptr, nullptr, L_SEQ, 512, 1024);
}

// Round 2
// 462.772 us; speedup vs baseline: 1.3441x; 1.3441x over previous
//
#include <hip/hip_runtime.h>
#include <stdint.h>

// ---------------------------------------------------------------------------
// MambaLikeBlock on MI355X (gfx950)
// R8: fix R7's scratch-spill. The bf16 epilogue's `for (p=0..1)` loop indexed
//     acc[p*4+i] with runtime p -> whole acc array demoted to scratch
//     (VGPR_Count=100, WRITE_SIZE 327MB, MfmaUtil 8%). Epilogue halves are
//     now hand-unrolled via macro so every acc index is a compile-time
//     literal. K-loop schedule (4-slot LDS ring, global_load_lds staging,
//     counted vmcnt, setprio) unchanged from R7.
// ---------------------------------------------------------------------------

#define L_SEQ 32768
#define CDIM 512
#define LN_EPS 1e-5f
#define CHUNK 64
#define NCHUNK (L_SEQ / CHUNK) // 512

typedef __attribute__((ext_vector_type(8))) short short8;
typedef __attribute__((ext_vector_type(4))) float floatx4;

__device__ inline unsigned short f2bf(float f) {
  union { float f; unsigned int u; } v; v.f = f;
  unsigned int r = v.u + 0x7fffu + ((v.u >> 16) & 1u);
  return (unsigned short)(r >> 16);
}
__device__ inline float bf2f(unsigned short h) {
  union { float f; unsigned int u; } v; v.u = ((unsigned int)h) << 16;
  return v.f;
}
__device__ inline float sigmoidf_(float x) { return 1.0f / (1.0f + __expf(-x)); }

// global -> LDS direct copy, 16B per lane. LDS dst is wave-uniform base +
// lane*16 (hardware); global src is per-lane (carries the swizzle).
__device__ __forceinline__ void gll16(const void* g, void* l) {
  __builtin_amdgcn_global_load_lds(
      (__attribute__((address_space(1))) void*)g,
      (__attribute__((address_space(3))) void*)l, 16, 0, 0);
}

// ---------------- LayerNorm: one wave per row (C=512 = 64 lanes x 8) -------
__global__ __launch_bounds__(256) void ln_kernel(const float* __restrict__ x,
    const float* __restrict__ w, const float* __restrict__ b,
    unsigned short* __restrict__ out) {
  int row = blockIdx.x * 4 + (threadIdx.x >> 6);
  int lane = threadIdx.x & 63;
  const float4* xr = (const float4*)(x + (size_t)row * CDIM);
  float4 v0 = xr[lane * 2];
  float4 v1 = xr[lane * 2 + 1];
  float s = v0.x + v0.y + v0.z + v0.w + v1.x + v1.y + v1.z + v1.w;
  float s2 = v0.x * v0.x + v0.y * v0.y + v0.z * v0.z + v0.w * v0.w +
             v1.x * v1.x + v1.y * v1.y + v1.z * v1.z + v1.w * v1.w;
  for (int m = 32; m > 0; m >>= 1) {
    s += __shfl_xor(s, m, 64);
    s2 += __shfl_xor(s2, m, 64);
  }
  float mean = s * (1.0f / CDIM);
  float var = s2 * (1.0f / CDIM) - mean * mean;
  float rs = rsqrtf(var + LN_EPS);
  const float4* wr = (const float4*)w;
  const float4* br = (const float4*)b;
  float4 w0 = wr[lane * 2], w1 = wr[lane * 2 + 1];
  float4 b0 = br[lane * 2], b1 = br[lane * 2 + 1];
  unsigned int p0 = (unsigned int)f2bf((v0.x - mean) * rs * w0.x + b0.x) |
                    ((unsigned int)f2bf((v0.y - mean) * rs * w0.y + b0.y) << 16);
  unsigned int p1 = (unsigned int)f2bf((v0.z - mean) * rs * w0.z + b0.z) |
                    ((unsigned int)f2bf((v0.w - mean) * rs * w0.w + b0.w) << 16);
  unsigned int p2 = (unsigned int)f2bf((v1.x - mean) * rs * w1.x + b1.x) |
                    ((unsigned int)f2bf((v1.y - mean) * rs * w1.y + b1.y) << 16);
  unsigned int p3 = (unsigned int)f2bf((v1.z - mean) * rs * w1.z + b1.z) |
                    ((unsigned int)f2bf((v1.w - mean) * rs * w1.w + b1.w) << 16);
  uint4 pk; pk.x = p0; pk.y = p1; pk.z = p2; pk.w = p3;
  *((uint4*)(out + (size_t)row * CDIM + lane * 8)) = pk;
}

// ---------------- Combined prep: 5 weight transposes + decay (1 launch) ----
__global__ __launch_bounds__(256) void prep_all(
    const float* __restrict__ W_in, const float* __restrict__ W_gate,
    const float* __restrict__ W_out, const float* __restrict__ W_ff1,
    const float* __restrict__ W_ff2, const float* __restrict__ logit,
    unsigned short* __restrict__ Wt_ig, unsigned short* __restrict__ Wt_out,
    unsigned short* __restrict__ Wt_ff1, unsigned short* __restrict__ Wt_ff2,
    float* __restrict__ decay, float* __restrict__ decayT) {
  int b = blockIdx.x;
  if (b >= 1792) { // decay prep
    for (int c = threadIdx.x; c < CDIM; c += 256) {
      float d = sigmoidf_(logit[c]);
      decay[c] = d;
      float p = d;
      for (int i = 0; i < 6; i++) p *= p; // d^64
      decayT[c] = p;
    }
    return;
  }
  const float* W; unsigned short* Wt; int Kd, Nd, t;
  if (b < 256)       { W = W_in;   Wt = Wt_ig;             Kd = 512;  Nd = 512;  t = b; }
  else if (b < 512)  { W = W_gate; Wt = Wt_ig + 512 * 512; Kd = 512;  Nd = 512;  t = b - 256; }
  else if (b < 768)  { W = W_out;  Wt = Wt_out;            Kd = 512;  Nd = 512;  t = b - 512; }
  else if (b < 1280) { W = W_ff1;  Wt = Wt_ff1;            Kd = 512;  Nd = 1024; t = b - 768; }
  else               { W = W_ff2;  Wt = Wt_ff2;            Kd = 1024; Nd = 512;  t = b - 1280; }
  int ntx = Nd >> 5;
  int n0 = (t % ntx) * 32, k0 = (t / ntx) * 32;
  __shared__ float tile[32][33];
  int tx = threadIdx.x & 31, ty = threadIdx.x >> 5; // 32x8
  for (int r = 0; r < 32; r += 8)
    tile[ty + r][tx] = W[(size_t)(k0 + ty + r) * Nd + n0 + tx];
  __syncthreads();
  for (int r = 0; r < 32; r += 8)
    Wt[(size_t)(n0 + ty + r) * Kd + k0 + tx] = f2bf(tile[tx][ty + r]);
}

// ---------------- bf16 MFMA GEMM: C = A(MxK) * Bt(NxK)^T + epilogue --------
// 256x256 tile, 512 threads = 8 waves (2M x 4N), per-wave 128x64 output
// (8x4 16x16 frags). BK=32. LDS: 4-slot ring for A and B (4 x 16 KB each,
// 128 KB total). Staging is global_load_lds (linear LDS dst, pre-swizzled
// global src); steady-state prefetch depth = 3 K-tiles, guarded by counted
// vmcnt (8 = 2 tiles x 4 loads outstanding allowed) + raw s_barrier.
// EPI 0: n<512 -> outU(bf16) = v+biasA[n]; n>=512 -> outG(bf16)=sigmoid(v+biasB)
// EPI 1: outF = res + v + biasA[n]           (float out, direct stores)
// EPI 2: outG = bf16(silu(v + biasA[n]))     (bf16 out, staged)
template <int EPI>
__global__ __launch_bounds__(512, 2) void gemm256(
    const unsigned short* __restrict__ A, const unsigned short* __restrict__ Bt,
    const float* __restrict__ biasA, const float* __restrict__ biasB,
    const float* __restrict__ res, float* __restrict__ outF,
    unsigned short* __restrict__ outU, unsigned short* __restrict__ outG,
    int M, int N, int K) {
  __shared__ unsigned short smem[65536];       // 128 KB
  unsigned short* As = smem;                   // 4 slots x 8192 elems
  unsigned short* Bs = smem + 32768;           // 4 slots x 8192 elems

  // XCD-aware remap (grid sizes 256/512 are both %8==0 -> bijective)
  int nbx = gridDim.x, nby = gridDim.y;
  int bid = blockIdx.x + blockIdx.y * nbx;
  int per = (nbx * nby) >> 3;
  int w = (bid & 7) * per + (bid >> 3);
  int ni = w % nby, mi = w / nby;
  int bm = mi << 8, bn = ni << 8;

  int tid = threadIdx.x, wave = tid >> 6, lane = tid & 63;
  int wm = (wave >> 2) * 128, wn = (wave & 3) * 64;
  int quad = lane >> 4, r16 = lane & 15;

  // ---- staging addressing ----
  // LDS slot layout (linear): elem = row*32 + chunk*8 + e, rows 0..255.
  // Stored data at [row][chunk] is global k-chunk (chunk ^ ((row>>1)&3)),
  // carried by pre-swizzling the global source column. Read side applies
  // the same XOR -> 2-way-max bank aliasing (free).
  int sr = tid >> 2;             // 0..127 (row within half-tile)
  int sc = tid & 3;              // dst chunk
  int swz = (sr >> 1) & 3;       // same for row sr and sr+128
  const unsigned short* aSrc0 = A + (size_t)(bm + sr) * K + ((sc ^ swz) * 8);
  const unsigned short* aSrc1 = aSrc0 + (size_t)128 * K;
  const unsigned short* bSrc0 = Bt + (size_t)(bn + sr) * K + ((sc ^ swz) * 8);
  const unsigned short* bSrc1 = bSrc0 + (size_t)128 * K;
  int ldsW = wave * 512;         // wave-uniform LDS base (elems); +lane*8 by HW

#define STAGE(slot, ktile) do {                                   \
    int _o = (ktile) * 32;                                        \
    unsigned short* _a = As + (slot) * 8192 + ldsW;               \
    unsigned short* _b = Bs + (slot) * 8192 + ldsW;               \
    gll16(aSrc0 + _o, _a);                                        \
    gll16(aSrc1 + _o, _a + 4096);                                 \
    gll16(bSrc0 + _o, _b);                                        \
    gll16(bSrc1 + _o, _b + 4096);                                 \
  } while (0)

  floatx4 acc[8][4];
#pragma unroll
  for (int i = 0; i < 8; i++)
#pragma unroll
    for (int j = 0; j < 4; j++) acc[i][j] = (floatx4){0.f, 0.f, 0.f, 0.f};

  // fragment read addressing (dewizzle): chunk = quad ^ ((r16>>1)&3)
  int cOff = ((quad ^ ((r16 >> 1) & 3)) & 3) * 8;
  int aBase = (wm + r16) * 32 + cOff;   // + i*512 per m-frag
  int bBase = (wn + r16) * 32 + cOff;   // + j*512 per n-frag

  int NK = K >> 5;  // 16 or 32; needs NK >= 4

  // prologue: stage tiles 0,1,2; wait tile0 (allow 2 tiles = 8 loads out)
  STAGE(0, 0); STAGE(1, 1); STAGE(2, 2);
  asm volatile("s_waitcnt vmcnt(8)" ::: "memory");
  __builtin_amdgcn_s_barrier();
  asm volatile("" ::: "memory");

  for (int j = 0; j < NK; ++j) {
    int slot = j & 3;
    if (j + 3 < NK) STAGE((j + 3) & 3, j + 3);   // ring: overwrites slot (j-1)&3
    const unsigned short* as = As + slot * 8192;
    const unsigned short* bs = Bs + slot * 8192;
    short8 af[8], bfr[4];
#pragma unroll
    for (int i = 0; i < 8; i++) af[i] = *(const short8*)(as + aBase + i * 512);
#pragma unroll
    for (int jj = 0; jj < 4; jj++) bfr[jj] = *(const short8*)(bs + bBase + jj * 512);
    if (j + 1 < NK) {
      // drain this wave's LDS reads (slot j gets overwritten next iter),
      // then guarantee tile j+1's staging landed, then barrier. Counted
      // vmcnt: outstanding allowed = newest tiles only (in-order completion).
      asm volatile("s_waitcnt lgkmcnt(0)" ::: "memory");
      if (j + 3 < NK)      asm volatile("s_waitcnt vmcnt(8)" ::: "memory");
      else if (j + 2 < NK) asm volatile("s_waitcnt vmcnt(4)" ::: "memory");
      else                 asm volatile("s_waitcnt vmcnt(0)" ::: "memory");
      __builtin_amdgcn_s_barrier();
      asm volatile("" ::: "memory");
    }
    __builtin_amdgcn_s_setprio(1);
#pragma unroll
    for (int i = 0; i < 8; i++)
#pragma unroll
      for (int jj = 0; jj < 4; jj++)
        acc[i][jj] = __builtin_amdgcn_mfma_f32_16x16x32_bf16(af[i], bfr[jj], acc[i][jj], 0, 0, 0);
    __builtin_amdgcn_s_setprio(0);
  }
#undef STAGE

  if (EPI == 1) {
    // fp32 output: 16 lanes x 4B = 64B segments, direct stores
#pragma unroll
    for (int i = 0; i < 8; i++) {
      int mb = bm + wm + i * 16 + quad * 4;
#pragma unroll
      for (int jj = 0; jj < 4; jj++) {
        int n = bn + wn + jj * 16 + r16;
        float bA = biasA[n];
#pragma unroll
        for (int r = 0; r < 4; r++) {
          size_t idx = (size_t)(mb + r) * N + n;
          outF[idx] = res[idx] + acc[i][jj][r] + bA;
        }
      }
    }
  } else {
    // bf16 output: stage half the tile (rows {0..63,128..191} then
    // {64..127,192..255}) in LDS, then coalesced 16B/lane stores.
    // NOTE: halves are macro-unrolled with literal P so every acc index is
    // compile-time-constant (runtime index would demote acc to scratch).
    unsigned short* sm16 = smem;   // 128 rows x 260 elems = 66.6 KB
#define EPI_HALF(P) {                                                        \
      __syncthreads(); /* P0: K-loop LDS reads done; P1: prior stores done */\
      _Pragma("unroll")                                                      \
      for (int jj = 0; jj < 4; jj++) {                                       \
        int colL = wn + jj * 16 + r16;                                       \
        int n = bn + colL;                                                   \
        _Pragma("unroll")                                                    \
        for (int i = 0; i < 4; i++) {                                        \
          int lr = (wm >> 1) + i * 16 + quad * 4;                            \
          _Pragma("unroll")                                                  \
          for (int r = 0; r < 4; r++) {                                      \
            float v = acc[(P) * 4 + i][jj][r];                               \
            float t;                                                         \
            if (EPI == 0) {                                                  \
              t = (n < 512) ? (v + biasA[n]) : sigmoidf_(v + biasB[n - 512]);\
            } else { /* EPI == 2 */                                          \
              float z = v + biasA[n];                                        \
              t = z * sigmoidf_(z);                                          \
            }                                                                \
            sm16[(lr + r) * 260 + colL] = f2bf(t);                           \
          }                                                                  \
        }                                                                    \
      }                                                                      \
      __syncthreads();                                                       \
      {                                                                      \
        int row = tid >> 2, c0 = (tid & 3) * 64;                             \
        int gr = bm + (row & 63) + ((row >> 6) * 128) + (P) * 64;            \
        const unsigned short* srcp = sm16 + row * 260 + c0;                  \
        unsigned short* gptr;                                                \
        if (EPI == 0) {                                                      \
          gptr = (bn < 512) ? (outU + (size_t)gr * 512 + bn + c0)            \
                            : (outG + (size_t)gr * 512 + (bn - 512) + c0);   \
        } else {                                                             \
          gptr = outG + (size_t)gr * N + bn + c0;                            \
        }                                                                    \
        _Pragma("unroll")                                                    \
        for (int s = 0; s < 8; s++)                                          \
          *(short8*)(gptr + s * 8) = *(const short8*)(srcp + s * 8);         \
      }                                                                      \
    }
    EPI_HALF(0)
    EPI_HALF(1)
#undef EPI_HALF
  }
}

// ---------------- Scan phase 1: per-chunk fwd/bwd aggregates ---------------
__global__ __launch_bounds__(512) void scan_phase1(const unsigned short* __restrict__ u,
    const float* __restrict__ decay, float* __restrict__ fa, float* __restrict__ ba) {
  int c = threadIdx.x, k = blockIdx.x;
  float d = decay[c];
  const unsigned short* up = u + (size_t)k * CHUNK * CDIM + c;
  float f = 0.f, bs = 0.f, p = 1.f;
#pragma unroll 8
  for (int t = 0; t < CHUNK; t++) {
    float v = bf2f(up[(size_t)t * CDIM]);
    f = d * f + v;
    bs += p * v;
    p *= d;
  }
  fa[(size_t)k * CDIM + c] = f;
  ba[(size_t)k * CDIM + c] = bs;
}

// ---------------- Scan phase 2: cross-chunk carries (fwd/bwd interleaved) --
__global__ __launch_bounds__(256) void scan_phase2(const float* __restrict__ fa,
    const float* __restrict__ ba, const float* __restrict__ decayT,
    float* __restrict__ fc, float* __restrict__ bc) {
  int c = blockIdx.x * 256 + threadIdx.x;
  float dT = decayT[c];
  float runf = 0.f, runb = 0.f;
#pragma unroll 4
  for (int k = 0; k < NCHUNK; k++) {
    int kb = NCHUNK - 1 - k;
    fc[(size_t)k * CDIM + c] = runf;
    runf = dT * runf + fa[(size_t)k * CDIM + c];
    bc[(size_t)kb * CDIM + c] = runb;
    runb = dT * runb + ba[(size_t)kb * CDIM + c];
  }
}

// ---------------- Scan phase 3: apply carries, combine, gate ---------------
__global__ __launch_bounds__(512) void scan_phase3(const unsigned short* __restrict__ u,
    const unsigned short* __restrict__ gate, const float* __restrict__ decay,
    const float* __restrict__ fc, const float* __restrict__ bc,
    unsigned short* __restrict__ state) {
  int c = threadIdx.x, k = blockIdx.x;
  float d = decay[c];
  size_t base = (size_t)k * CHUNK * CDIM + c;
  float fwd[CHUNK];
  float run = fc[(size_t)k * CDIM + c];
#pragma unroll
  for (int t = 0; t < CHUNK; t++) {
    run = d * run + bf2f(u[base + (size_t)t * CDIM]);
    fwd[t] = run;
  }
  float runb = bc[(size_t)k * CDIM + c];
#pragma unroll
  for (int t = CHUNK - 1; t >= 0; t--) {
    runb = d * runb + bf2f(u[base + (size_t)t * CDIM]);
    float g = bf2f(gate[base + (size_t)t * CDIM]);
    state[base + (size_t)t * CDIM] = f2bf(0.5f * (fwd[t] + runb) * g);
  }
}

// ---------------------------------------------------------------------------
extern "C" void kernel_launch(void* const* d_in, const int* in_sizes, int n_in,
                              void* d_out, int out_size, void* d_ws, size_t ws_size,
                              hipStream_t stream) {
  const float* x = (const float*)d_in[0];
  const float* ln1_w = (const float*)d_in[1];
  const float* ln1_b = (const float*)d_in[2];
  const float* W_in = (const float*)d_in[3];
  const float* b_in = (const float*)d_in[4];
  const float* W_gate = (const float*)d_in[5];
  const float* b_gate = (const float*)d_in[6];
  const float* W_out = (const float*)d_in[7];
  const float* b_out = (const float*)d_in[8];
  const float* decay_logit = (const float*)d_in[9];
  const float* ln2_w = (const float*)d_in[10];
  const float* ln2_b = (const float*)d_in[11];
  const float* W_ff1 = (const float*)d_in[12];
  const float* b_ff1 = (const float*)d_in[13];
  const float* W_ff2 = (const float*)d_in[14];
  const float* b_ff2 = (const float*)d_in[15];

  char* ws = (char*)d_ws;
  size_t off = 0;
  auto alloc = [&](size_t bytes) -> void* {
    void* p = ws + off;
    off += (bytes + 255) & ~(size_t)255;
    return p;
  };
  // --- small persistent buffers (~8.5 MB) ---
  unsigned short* Wt_ig  = (unsigned short*)alloc((size_t)1024 * 512 * 2);
  unsigned short* Wt_out = (unsigned short*)alloc((size_t)512 * 512 * 2);
  unsigned short* Wt_ff1 = (unsigned short*)alloc((size_t)1024 * 512 * 2);
  unsigned short* Wt_ff2 = (unsigned short*)alloc((size_t)512 * 1024 * 2);
  float* fa = (float*)alloc((size_t)NCHUNK * CDIM * 4);
  float* ba = (float*)alloc((size_t)NCHUNK * CDIM * 4);
  float* fc = (float*)alloc((size_t)NCHUNK * CDIM * 4);
  float* bc = (float*)alloc((size_t)NCHUNK * CDIM * 4);
  float* decay  = (float*)alloc(CDIM * 4);
  float* decayT = (float*)alloc(CDIM * 4);
  // --- large aliased regions (liveness-disjoint) ---
  const size_t LC2 = (size_t)L_SEQ * CDIM * 2; // 33.55 MB
  unsigned short* R1 = (unsigned short*)alloc(LC2);      // hidden -> state -> hbuf
  unsigned short* R2 = (unsigned short*)alloc(LC2);      // u(bf16) -> ffb[0:]
  unsigned short* R3 = (unsigned short*)alloc(LC2);      // gate    -> ffb[L*C:]
  unsigned short* hidden = R1;
  unsigned short* state  = R1;
  unsigned short* hbuf   = R1;
  unsigned short* u_buf  = R2;
  unsigned short* gate   = R3;
  unsigned short* ffb    = R2; // 67 MB spanning R2+R3 (contiguous)
  float* x2 = (float*)d_out;   // d_out doubles as x2 buffer

  // single prep launch: all transposes + decay
  prep_all<<<1793, 256, 0, stream>>>(W_in, W_gate, W_out, W_ff1, W_ff2,
      decay_logit, Wt_ig, Wt_out, Wt_ff1, Wt_ff2, decay, decayT);

  // LN1
  ln_kernel<<<L_SEQ / 4, 256, 0, stream>>>(x, ln1_w, ln1_b, hidden);

  // u | gate fused GEMM (N=1024); grid = (M/256, N/256)
  gemm256<0><<<dim3(L_SEQ / 256, 1024 / 256), 512, 0, stream>>>(
      hidden, Wt_ig, b_in, b_gate, nullptr, nullptr, u_buf, gate, L_SEQ, 1024, 512);

  // bidirectional scan
  scan_phase1<<<NCHUNK, 512, 0, stream>>>(u_buf, decay, fa, ba);
  scan_phase2<<<2, 256, 0, stream>>>(fa, ba, decayT, fc, bc);
  scan_phase3<<<NCHUNK, 512, 0, stream>>>(u_buf, gate, decay, fc, bc, state);

  // x2 = x + state @ W_out + b_out   (written to d_out)
  gemm256<1><<<dim3(L_SEQ / 256, 512 / 256), 512, 0, stream>>>(
      state, Wt_out, b_out, nullptr, x, x2, nullptr, nullptr, L_SEQ, 512, 512);

  // LN2
  ln_kernel<<<L_SEQ / 4, 256, 0, stream>>>(x2, ln2_w, ln2_b, hbuf);

  // ff = silu(h @ W_ff1 + b_ff1)
  gemm256<2><<<dim3(L_SEQ / 256, 1024 / 256), 512, 0, stream>>>(
      hbuf, Wt_ff1, b_ff1, nullptr, nullptr, nullptr, nullptr, ffb, L_SEQ, 1024, 512);

  // out = x2 + ff @ W_ff2 + b_ff2   (in-place read/write on d_out is per-element safe)
  gemm256<1><<<dim3(L_SEQ / 256, 512 / 256), 512, 0, stream>>>(
      ffb, Wt_ff2, b_ff2, nullptr, x2, x2, nullptr, nullptr, L_SEQ, 512, 1024);
}

// Round 3
// 459.728 us; speedup vs baseline: 1.3530x; 1.0066x over previous
//
#include <hip/hip_runtime.h>
#include <stdint.h>

// ---------------------------------------------------------------------------
// MambaLikeBlock on MI355X (gfx950)
// R9: K-loop restructured into 4 role-split phases per iteration:
//     {asm ds_read_b128 frags -> 1 global_load_lds -> lgkmcnt(0) ->
//      sched_barrier(0) -> setprio(1) -> 8 MFMA -> setprio(0)} x4,
//     ONE s_barrier + counted vmcnt(8/4/0) per iteration. All K-loop memory
//     ops are inline-asm/intrinsics so the compiler cannot insert phantom
//     vmcnt(0) drains between gload_lds (LDS write) and the LDS frag reads
//     (same smem object -> no alias disambiguation). R8 measured 6950
//     cyc/iter vs 1242 cyc MFMA content = ~5700-cyc stall consistent with a
//     per-iter full vmem drain. Ring WAR safety: stage targets slot j+3;
//     all reads of a slot complete before each wave's lgkmcnt(0), and the
//     end-of-iter barrier bounds wave drift below one iteration.
// ---------------------------------------------------------------------------

#define L_SEQ 32768
#define CDIM 512
#define LN_EPS 1e-5f
#define CHUNK 64
#define NCHUNK (L_SEQ / CHUNK) // 512

typedef __attribute__((ext_vector_type(8))) short short8;
typedef __attribute__((ext_vector_type(4))) float floatx4;
typedef __attribute__((ext_vector_type(4))) int intx4;

__device__ inline unsigned short f2bf(float f) {
  union { float f; unsigned int u; } v; v.f = f;
  unsigned int r = v.u + 0x7fffu + ((v.u >> 16) & 1u);
  return (unsigned short)(r >> 16);
}
__device__ inline float bf2f(unsigned short h) {
  union { float f; unsigned int u; } v; v.u = ((unsigned int)h) << 16;
  return v.f;
}
__device__ inline float sigmoidf_(float x) { return 1.0f / (1.0f + __expf(-x)); }
__device__ __forceinline__ short8 asS8(intx4 v) {
  union { intx4 i; short8 s; } u; u.i = v; return u.s;
}

// global -> LDS direct copy, 16B per lane.
__device__ __forceinline__ void gll16(const void* g, void* l) {
  __builtin_amdgcn_global_load_lds(
      (__attribute__((address_space(1))) void*)g,
      (__attribute__((address_space(3))) void*)l, 16, 0, 0);
}

// ---------------- LayerNorm: one wave per row (C=512 = 64 lanes x 8) -------
__global__ __launch_bounds__(256) void ln_kernel(const float* __restrict__ x,
    const float* __restrict__ w, const float* __restrict__ b,
    unsigned short* __restrict__ out) {
  int row = blockIdx.x * 4 + (threadIdx.x >> 6);
  int lane = threadIdx.x & 63;
  const float4* xr = (const float4*)(x + (size_t)row * CDIM);
  float4 v0 = xr[lane * 2];
  float4 v1 = xr[lane * 2 + 1];
  float s = v0.x + v0.y + v0.z + v0.w + v1.x + v1.y + v1.z + v1.w;
  float s2 = v0.x * v0.x + v0.y * v0.y + v0.z * v0.z + v0.w * v0.w +
             v1.x * v1.x + v1.y * v1.y + v1.z * v1.z + v1.w * v1.w;
  for (int m = 32; m > 0; m >>= 1) {
    s += __shfl_xor(s, m, 64);
    s2 += __shfl_xor(s2, m, 64);
  }
  float mean = s * (1.0f / CDIM);
  float var = s2 * (1.0f / CDIM) - mean * mean;
  float rs = rsqrtf(var + LN_EPS);
  const float4* wr = (const float4*)w;
  const float4* br = (const float4*)b;
  float4 w0 = wr[lane * 2], w1 = wr[lane * 2 + 1];
  float4 b0 = br[lane * 2], b1 = br[lane * 2 + 1];
  unsigned int p0 = (unsigned int)f2bf((v0.x - mean) * rs * w0.x + b0.x) |
                    ((unsigned int)f2bf((v0.y - mean) * rs * w0.y + b0.y) << 16);
  unsigned int p1 = (unsigned int)f2bf((v0.z - mean) * rs * w0.z + b0.z) |
                    ((unsigned int)f2bf((v0.w - mean) * rs * w0.w + b0.w) << 16);
  unsigned int p2 = (unsigned int)f2bf((v1.x - mean) * rs * w1.x + b1.x) |
                    ((unsigned int)f2bf((v1.y - mean) * rs * w1.y + b1.y) << 16);
  unsigned int p3 = (unsigned int)f2bf((v1.z - mean) * rs * w1.z + b1.z) |
                    ((unsigned int)f2bf((v1.w - mean) * rs * w1.w + b1.w) << 16);
  uint4 pk; pk.x = p0; pk.y = p1; pk.z = p2; pk.w = p3;
  *((uint4*)(out + (size_t)row * CDIM + lane * 8)) = pk;
}

// ---------------- Combined prep: 5 weight transposes + decay (1 launch) ----
__global__ __launch_bounds__(256) void prep_all(
    const float* __restrict__ W_in, const float* __restrict__ W_gate,
    const float* __restrict__ W_out, const float* __restrict__ W_ff1,
    const float* __restrict__ W_ff2, const float* __restrict__ logit,
    unsigned short* __restrict__ Wt_ig, unsigned short* __restrict__ Wt_out,
    unsigned short* __restrict__ Wt_ff1, unsigned short* __restrict__ Wt_ff2,
    float* __restrict__ decay, float* __restrict__ decayT) {
  int b = blockIdx.x;
  if (b >= 1792) { // decay prep
    for (int c = threadIdx.x; c < CDIM; c += 256) {
      float d = sigmoidf_(logit[c]);
      decay[c] = d;
      float p = d;
      for (int i = 0; i < 6; i++) p *= p; // d^64
      decayT[c] = p;
    }
    return;
  }
  const float* W; unsigned short* Wt; int Kd, Nd, t;
  if (b < 256)       { W = W_in;   Wt = Wt_ig;             Kd = 512;  Nd = 512;  t = b; }
  else if (b < 512)  { W = W_gate; Wt = Wt_ig + 512 * 512; Kd = 512;  Nd = 512;  t = b - 256; }
  else if (b < 768)  { W = W_out;  Wt = Wt_out;            Kd = 512;  Nd = 512;  t = b - 512; }
  else if (b < 1280) { W = W_ff1;  Wt = Wt_ff1;            Kd = 512;  Nd = 1024; t = b - 768; }
  else               { W = W_ff2;  Wt = Wt_ff2;            Kd = 1024; Nd = 512;  t = b - 1280; }
  int ntx = Nd >> 5;
  int n0 = (t % ntx) * 32, k0 = (t / ntx) * 32;
  __shared__ float tile[32][33];
  int tx = threadIdx.x & 31, ty = threadIdx.x >> 5; // 32x8
  for (int r = 0; r < 32; r += 8)
    tile[ty + r][tx] = W[(size_t)(k0 + ty + r) * Nd + n0 + tx];
  __syncthreads();
  for (int r = 0; r < 32; r += 8)
    Wt[(size_t)(n0 + ty + r) * Kd + k0 + tx] = f2bf(tile[tx][ty + r]);
}

// ---------------- bf16 MFMA GEMM: C = A(MxK) * Bt(NxK)^T + epilogue --------
// 256x256 tile, 512 threads = 8 waves (2M x 4N), per-wave 128x64 output
// (8x4 16x16 frags). BK=32. LDS: 4-slot ring for A and B (128 KB total).
// K-iteration = 4 phases (see header comment); ONE barrier + counted vmcnt
// per iteration. EPI as before.
template <int EPI>
__global__ __launch_bounds__(512, 2) void gemm256(
    const unsigned short* __restrict__ A, const unsigned short* __restrict__ Bt,
    const float* __restrict__ biasA, const float* __restrict__ biasB,
    const float* __restrict__ res, float* __restrict__ outF,
    unsigned short* __restrict__ outU, unsigned short* __restrict__ outG,
    int M, int N, int K) {
  __shared__ unsigned short smem[65536];       // 128 KB
  unsigned short* As = smem;                   // 4 slots x 8192 elems
  unsigned short* Bs = smem + 32768;           // 4 slots x 8192 elems

  // XCD-aware remap (grid sizes 256/512 are both %8==0 -> bijective)
  int nbx = gridDim.x, nby = gridDim.y;
  int bid = blockIdx.x + blockIdx.y * nbx;
  int per = (nbx * nby) >> 3;
  int w = (bid & 7) * per + (bid >> 3);
  int ni = w % nby, mi = w / nby;
  int bm = mi << 8, bn = ni << 8;

  int tid = threadIdx.x, wave = tid >> 6, lane = tid & 63;
  int wm = (wave >> 2) * 128, wn = (wave & 3) * 64;
  int quad = lane >> 4, r16 = lane & 15;

  // ---- staging addressing (same swizzle as R8; measured 0 conflicts) ----
  int sr = tid >> 2;             // 0..127 (row within half-tile)
  int sc = tid & 3;              // dst chunk
  int swz = (sr >> 1) & 3;
  const unsigned short* aSrc0 = A + (size_t)(bm + sr) * K + ((sc ^ swz) * 8);
  const unsigned short* aSrc1 = aSrc0 + (size_t)128 * K;
  const unsigned short* bSrc0 = Bt + (size_t)(bn + sr) * K + ((sc ^ swz) * 8);
  const unsigned short* bSrc1 = bSrc0 + (size_t)128 * K;
  int ldsW = wave * 512;         // wave-uniform LDS base (elems)

#define STAGE4(slot, ktile) do {                                  \
    int _o = (ktile) * 32;                                        \
    unsigned short* _a = As + (slot) * 8192 + ldsW;               \
    unsigned short* _b = Bs + (slot) * 8192 + ldsW;               \
    gll16(aSrc0 + _o, _a);                                        \
    gll16(aSrc1 + _o, _a + 4096);                                 \
    gll16(bSrc0 + _o, _b);                                        \
    gll16(bSrc1 + _o, _b + 4096);                                 \
  } while (0)

  floatx4 acc[8][4];
#pragma unroll
  for (int i = 0; i < 8; i++)
#pragma unroll
    for (int j = 0; j < 4; j++) acc[i][j] = (floatx4){0.f, 0.f, 0.f, 0.f};

  // fragment read addressing (dewizzle): chunk = quad ^ ((r16>>1)&3)
  int cOff = ((quad ^ ((r16 >> 1) & 3)) & 3) * 8;
  unsigned aByte = (unsigned)(((wm + r16) * 32 + cOff) * 2);            // As elem*2
  unsigned bByte = 65536u + (unsigned)(((wn + r16) * 32 + cOff) * 2);   // Bs base

  int NK = K >> 5;  // 16 or 32; needs NK >= 4

  // asm ds_read_b128 from LDS byte offset (AS3 pointer -> 32-bit vaddr)
#define DSR(dst, byteOff) asm volatile("ds_read_b128 %0, %1"              \
    : "=v"(dst)                                                           \
    : "v"((__attribute__((address_space(3))) const void*)                 \
          ((const char*)smem + (byteOff))))

#define LGKM0_FENCE() do {                                                \
    asm volatile("s_waitcnt lgkmcnt(0)" ::: "memory");                    \
    __builtin_amdgcn_sched_barrier(0);                                    \
  } while (0)

#define MFMA8(Q, A0, A1) do {                                             \
    __builtin_amdgcn_s_setprio(1);                                        \
    short8 _a0 = asS8(A0), _a1 = asS8(A1);                                \
    short8 _b0 = asS8(tb0), _b1 = asS8(tb1), _b2 = asS8(tb2), _b3 = asS8(tb3); \
    acc[2*(Q)  ][0] = __builtin_amdgcn_mfma_f32_16x16x32_bf16(_a0, _b0, acc[2*(Q)  ][0], 0, 0, 0); \
    acc[2*(Q)  ][1] = __builtin_amdgcn_mfma_f32_16x16x32_bf16(_a0, _b1, acc[2*(Q)  ][1], 0, 0, 0); \
    acc[2*(Q)  ][2] = __builtin_amdgcn_mfma_f32_16x16x32_bf16(_a0, _b2, acc[2*(Q)  ][2], 0, 0, 0); \
    acc[2*(Q)  ][3] = __builtin_amdgcn_mfma_f32_16x16x32_bf16(_a0, _b3, acc[2*(Q)  ][3], 0, 0, 0); \
    acc[2*(Q)+1][0] = __builtin_amdgcn_mfma_f32_16x16x32_bf16(_a1, _b0, acc[2*(Q)+1][0], 0, 0, 0); \
    acc[2*(Q)+1][1] = __builtin_amdgcn_mfma_f32_16x16x32_bf16(_a1, _b1, acc[2*(Q)+1][1], 0, 0, 0); \
    acc[2*(Q)+1][2] = __builtin_amdgcn_mfma_f32_16x16x32_bf16(_a1, _b2, acc[2*(Q)+1][2], 0, 0, 0); \
    acc[2*(Q)+1][3] = __builtin_amdgcn_mfma_f32_16x16x32_bf16(_a1, _b3, acc[2*(Q)+1][3], 0, 0, 0); \
    __builtin_amdgcn_s_setprio(0);                                        \
  } while (0)

  // prologue: stage tiles 0,1,2; wait tile0 (allow 8 = tiles 1,2 in flight)
  STAGE4(0, 0); STAGE4(1, 1); STAGE4(2, 2);
  asm volatile("s_waitcnt vmcnt(8)" ::: "memory");
  __builtin_amdgcn_s_barrier();

  intx4 tb0, tb1, tb2, tb3;
  for (int j = 0; j < NK; ++j) {
    int slot = j & 3;
    unsigned so = (unsigned)slot * 16384u;
    unsigned aA = aByte + so, bA = bByte + so;
    bool st = (j + 3 < NK);
    int o3 = (j + 3) * 32;
    int s3 = (j + 3) & 3;
    unsigned short* a3 = As + s3 * 8192 + ldsW;
    unsigned short* b3 = Bs + s3 * 8192 + ldsW;

    // ---- phase 0: B frags + A m0,m1; stage A-half0 of tile j+3 ----
    intx4 t0, t1;
    DSR(tb0, bA);
    DSR(tb1, bA + 1024u);
    DSR(tb2, bA + 2048u);
    DSR(tb3, bA + 3072u);
    DSR(t0, aA);
    DSR(t1, aA + 1024u);
    if (st) gll16(aSrc0 + o3, a3);
    LGKM0_FENCE();
    MFMA8(0, t0, t1);

    // ---- phase 1: A m2,m3; stage A-half1 ----
    intx4 t2, t3;
    DSR(t2, aA + 2048u);
    DSR(t3, aA + 3072u);
    if (st) gll16(aSrc1 + o3, a3 + 4096);
    LGKM0_FENCE();
    MFMA8(1, t2, t3);

    // ---- phase 2: A m4,m5; stage B-half0 ----
    intx4 t4, t5;
    DSR(t4, aA + 4096u);
    DSR(t5, aA + 5120u);
    if (st) gll16(bSrc0 + o3, b3);
    LGKM0_FENCE();
    MFMA8(2, t4, t5);

    // ---- phase 3: A m6,m7; stage B-half1; counted vmcnt; barrier ----
    intx4 t6, t7;
    DSR(t6, aA + 6144u);
    DSR(t7, aA + 7168u);
    if (st) gll16(bSrc1 + o3, b3 + 4096);
    if (st)                  asm volatile("s_waitcnt vmcnt(8)" ::: "memory");
    else if (j + 2 < NK)     asm volatile("s_waitcnt vmcnt(4)" ::: "memory");
    else if (j + 1 < NK)     asm volatile("s_waitcnt vmcnt(0)" ::: "memory");
    LGKM0_FENCE();
    MFMA8(3, t6, t7);
    __builtin_amdgcn_s_barrier();
  }
#undef STAGE4
#undef DSR
#undef LGKM0_FENCE
#undef MFMA8

  if (EPI == 1) {
    // fp32 output: 16 lanes x 4B = 64B segments, direct stores
#pragma unroll
    for (int i = 0; i < 8; i++) {
      int mb = bm + wm + i * 16 + quad * 4;
#pragma unroll
      for (int jj = 0; jj < 4; jj++) {
        int n = bn + wn + jj * 16 + r16;
        float bA = biasA[n];
#pragma unroll
        for (int r = 0; r < 4; r++) {
          size_t idx = (size_t)(mb + r) * N + n;
          outF[idx] = res[idx] + acc[i][jj][r] + bA;
        }
      }
    }
  } else {
    // bf16 output: stage half the tile in LDS, then coalesced 16B/lane
    // stores. Halves macro-unrolled with literal P (rule #20).
    unsigned short* sm16 = smem;   // 128 rows x 260 elems = 66.6 KB
#define EPI_HALF(P) {                                                        \
      __syncthreads(); /* P0: K-loop LDS reads done; P1: prior stores done */\
      _Pragma("unroll")                                                      \
      for (int jj = 0; jj < 4; jj++) {                                       \
        int colL = wn + jj * 16 + r16;                                       \
        int n = bn + colL;                                                   \
        _Pragma("unroll")                                                    \
        for (int i = 0; i < 4; i++) {                                        \
          int lr = (wm >> 1) + i * 16 + quad * 4;                            \
          _Pragma("unroll")                                                  \
          for (int r = 0; r < 4; r++) {                                      \
            float v = acc[(P) * 4 + i][jj][r];                               \
            float t;                                                         \
            if (EPI == 0) {                                                  \
              t = (n < 512) ? (v + biasA[n]) : sigmoidf_(v + biasB[n - 512]);\
            } else { /* EPI == 2 */                                          \
              float z = v + biasA[n];                                        \
              t = z * sigmoidf_(z);                                          \
            }                                                                \
            sm16[(lr + r) * 260 + colL] = f2bf(t);                           \
          }                                                                  \
        }                                                                    \
      }                                                                      \
      __syncthreads();                                                       \
      {                                                                      \
        int row = tid >> 2, c0 = (tid & 3) * 64;                             \
        int gr = bm + (row & 63) + ((row >> 6) * 128) + (P) * 64;            \
        const unsigned short* srcp = sm16 + row * 260 + c0;                  \
        unsigned short* gptr;                                                \
        if (EPI == 0) {                                                      \
          gptr = (bn < 512) ? (outU + (size_t)gr * 512 + bn + c0)            \
                            : (outG + (size_t)gr * 512 + (bn - 512) + c0);   \
        } else {                                                             \
          gptr = outG + (size_t)gr * N + bn + c0;                            \
        }                                                                    \
        _Pragma("unroll")                                                    \
        for (int s = 0; s < 8; s++)                                          \
          *(short8*)(gptr + s * 8) = *(const short8*)(srcp + s * 8);         \
      }                                                                      \
    }
    EPI_HALF(0)
    EPI_HALF(1)
#undef EPI_HALF
  }
}

// ---------------- Scan phase 1: per-chunk fwd/bwd aggregates ---------------
__global__ __launch_bounds__(512) void scan_phase1(const unsigned short* __restrict__ u,
    const float* __restrict__ decay, float* __restrict__ fa, float* __restrict__ ba) {
  int c = threadIdx.x, k = blockIdx.x;
  float d = decay[c];
  const unsigned short* up = u + (size_t)k * CHUNK * CDIM + c;
  float f = 0.f, bs = 0.f, p = 1.f;
#pragma unroll 8
  for (int t = 0; t < CHUNK; t++) {
    float v = bf2f(up[(size_t)t * CDIM]);
    f = d * f + v;
    bs += p * v;
    p *= d;
  }
  fa[(size_t)k * CDIM + c] = f;
  ba[(size_t)k * CDIM + c] = bs;
}

// ---------------- Scan phase 2: cross-chunk carries (fwd/bwd interleaved) --
__global__ __launch_bounds__(256) void scan_phase2(const float* __restrict__ fa,
    const float* __restrict__ ba, const float* __restrict__ decayT,
    float* __restrict__ fc, float* __restrict__ bc) {
  int c = blockIdx.x * 256 + threadIdx.x;
  float dT = decayT[c];
  float runf = 0.f, runb = 0.f;
#pragma unroll 4
  for (int k = 0; k < NCHUNK; k++) {
    int kb = NCHUNK - 1 - k;
    fc[(size_t)k * CDIM + c] = runf;
    runf = dT * runf + fa[(size_t)k * CDIM + c];
    bc[(size_t)kb * CDIM + c] = runb;
    runb = dT * runb + ba[(size_t)kb * CDIM + c];
  }
}

// ---------------- Scan phase 3: apply carries, combine, gate ---------------
__global__ __launch_bounds__(512) void scan_phase3(const unsigned short* __restrict__ u,
    const unsigned short* __restrict__ gate, const float* __restrict__ decay,
    const float* __restrict__ fc, const float* __restrict__ bc,
    unsigned short* __restrict__ state) {
  int c = threadIdx.x, k = blockIdx.x;
  float d = decay[c];
  size_t base = (size_t)k * CHUNK * CDIM + c;
  float fwd[CHUNK];
  float run = fc[(size_t)k * CDIM + c];
#pragma unroll
  for (int t = 0; t < CHUNK; t++) {
    run = d * run + bf2f(u[base + (size_t)t * CDIM]);
    fwd[t] = run;
  }
  float runb = bc[(size_t)k * CDIM + c];
#pragma unroll
  for (int t = CHUNK - 1; t >= 0; t--) {
    runb = d * runb + bf2f(u[base + (size_t)t * CDIM]);
    float g = bf2f(gate[base + (size_t)t * CDIM]);
    state[base + (size_t)t * CDIM] = f2bf(0.5f * (fwd[t] + runb) * g);
  }
}

// ---------------------------------------------------------------------------
extern "C" void kernel_launch(void* const* d_in, const int* in_sizes, int n_in,
                              void* d_out, int out_size, void* d_ws, size_t ws_size,
                              hipStream_t stream) {
  const float* x = (const float*)d_in[0];
  const float* ln1_w = (const float*)d_in[1];
  const float* ln1_b = (const float*)d_in[2];
  const float* W_in = (const float*)d_in[3];
  const float* b_in = (const float*)d_in[4];
  const float* W_gate = (const float*)d_in[5];
  const float* b_gate = (const float*)d_in[6];
  const float* W_out = (const float*)d_in[7];
  const float* b_out = (const float*)d_in[8];
  const float* decay_logit = (const float*)d_in[9];
  const float* ln2_w = (const float*)d_in[10];
  const float* ln2_b = (const float*)d_in[11];
  const float* W_ff1 = (const float*)d_in[12];
  const float* b_ff1 = (const float*)d_in[13];
  const float* W_ff2 = (const float*)d_in[14];
  const float* b_ff2 = (const float*)d_in[15];

  char* ws = (char*)d_ws;
  size_t off = 0;
  auto alloc = [&](size_t bytes) -> void* {
    void* p = ws + off;
    off += (bytes + 255) & ~(size_t)255;
    return p;
  };
  // --- small persistent buffers (~8.5 MB) ---
  unsigned short* Wt_ig  = (unsigned short*)alloc((size_t)1024 * 512 * 2);
  unsigned short* Wt_out = (unsigned short*)alloc((size_t)512 * 512 * 2);
  unsigned short* Wt_ff1 = (unsigned short*)alloc((size_t)1024 * 512 * 2);
  unsigned short* Wt_ff2 = (unsigned short*)alloc((size_t)512 * 1024 * 2);
  float* fa = (float*)alloc((size_t)NCHUNK * CDIM * 4);
  float* ba = (float*)alloc((size_t)NCHUNK * CDIM * 4);
  float* fc = (float*)alloc((size_t)NCHUNK * CDIM * 4);
  float* bc = (float*)alloc((size_t)NCHUNK * CDIM * 4);
  float* decay  = (float*)alloc(CDIM * 4);
  float* decayT = (float*)alloc(CDIM * 4);
  // --- large aliased regions (liveness-disjoint) ---
  const size_t LC2 = (size_t)L_SEQ * CDIM * 2; // 33.55 MB
  unsigned short* R1 = (unsigned short*)alloc(LC2);      // hidden -> state -> hbuf
  unsigned short* R2 = (unsigned short*)alloc(LC2);      // u(bf16) -> ffb[0:]
  unsigned short* R3 = (unsigned short*)alloc(LC2);      // gate    -> ffb[L*C:]
  unsigned short* hidden = R1;
  unsigned short* state  = R1;
  unsigned short* hbuf   = R1;
  unsigned short* u_buf  = R2;
  unsigned short* gate   = R3;
  unsigned short* ffb    = R2; // 67 MB spanning R2+R3 (contiguous)
  float* x2 = (float*)d_out;   // d_out doubles as x2 buffer

  // single prep launch: all transposes + decay
  prep_all<<<1793, 256, 0, stream>>>(W_in, W_gate, W_out, W_ff1, W_ff2,
      decay_logit, Wt_ig, Wt_out, Wt_ff1, Wt_ff2, decay, decayT);

  // LN1
  ln_kernel<<<L_SEQ / 4, 256, 0, stream>>>(x, ln1_w, ln1_b, hidden);

  // u | gate fused GEMM (N=1024); grid = (M/256, N/256)
  gemm256<0><<<dim3(L_SEQ / 256, 1024 / 256), 512, 0, stream>>>(
      hidden, Wt_ig, b_in, b_gate, nullptr, nullptr, u_buf, gate, L_SEQ, 1024, 512);

  // bidirectional scan
  scan_phase1<<<NCHUNK, 512, 0, stream>>>(u_buf, decay, fa, ba);
  scan_phase2<<<2, 256, 0, stream>>>(fa, ba, decayT, fc, bc);
  scan_phase3<<<NCHUNK, 512, 0, stream>>>(u_buf, gate, decay, fc, bc, state);

  // x2 = x + state @ W_out + b_out   (written to d_out)
  gemm256<1><<<dim3(L_SEQ / 256, 512 / 256), 512, 0, stream>>>(
      state, Wt_out, b_out, nullptr, x, x2, nullptr, nullptr, L_SEQ, 512, 512);

  // LN2
  ln_kernel<<<L_SEQ / 4, 256, 0, stream>>>(x2, ln2_w, ln2_b, hbuf);

  // ff = silu(h @ W_ff1 + b_ff1)
  gemm256<2><<<dim3(L_SEQ / 256, 1024 / 256), 512, 0, stream>>>(
      hbuf, Wt_ff1, b_ff1, nullptr, nullptr, nullptr, nullptr, ffb, L_SEQ, 1024, 512);

  // out = x2 + ff @ W_ff2 + b_ff2   (in-place read/write on d_out is per-element safe)
  gemm256<1><<<dim3(L_SEQ / 256, 512 / 256), 512, 0, stream>>>(
      ffb, Wt_ff2, b_ff2, nullptr, x2, x2, nullptr, nullptr, L_SEQ, 512, 1024);
}